// Round 5
// baseline (360.645 us; speedup 1.0000x reference)
//
#include <hip/hip_runtime.h>
#include <math.h>

typedef float v4f __attribute__((ext_vector_type(4)));

#define XS 2048
#define NN 4096
#define ZS 64
#define DD 6208
#define D4 1552              // DD/4 chunks per row
#define Z0 (XS + NN)         // 6144
#define TOPK 16
#define ZTOPK 8
#define EPS_TIE 1e-9f
#define RNDC 0.5f
#define NXUPD 2047           // x rows updated: 0..2046

// d_out offsets (floats): [z_response(64) | final(6208) | neurons(DD*DD) | ages(6208)]
#define OUT_FINAL 64
#define OUT_NEUR  (64 + DD)
#define OUT_AGES  (OUT_NEUR + (size_t)DD * DD)

// ws offsets (floats) — no region requires pre-zeroing by the host
#define WS_RESP    0                         // [0,2048): xsum (phase B); [2048,6208): yz dots (phase A)
#define WS_RESPP   DD                        // 4 x 2048 x-row dot partials
#define WS_INPT    (DD + 8192)
#define WS_MIXX    (WS_INPT + DD)
#define WS_MIXZ    (WS_MIXX + DD)
#define WS_MIXY    (WS_MIXZ + DD)
#define WS_SCAL    (WS_MIXY + DD)            // [7] = denomX (written by phase B)
#define WS_SCALPAD (WS_SCAL + 32)            // 7 scalars x 64 slots (zeroed by phase B blk3)
#define WS_SELROW  (WS_SCALPAD + 448)        // 24 ints
#define WS_SELC    (WS_SELROW + 24)          // 24 floats: v/a
#define WS_SELW    (WS_SELC + 24)            // 24 floats: (a-1)/a
#define WS_TOTAL   (WS_SELW + 32)

// scalpad scalar ids: 0 Sii, 1 SmmX, 2 SmiX, 3 SmmZ, 4 SmiZ, 5 SmmY, 6 SmiY

// phase A: 256 row-groups (8 rows) x 4 col splits + 4160 yz rows + 11 aux
#define XBLKS 1024
#define CSPL  388
#define YZBLKS (DD - XS)             // 4160
#define AUXBLKS 11
#define NVB_A (XBLKS + YZBLKS + AUXBLKS)   // 5195

// phase C: 388 mix_x reduce + 16 gather
#define RBLKS 388
#define GBLKS 16
#define NVB_C (RBLKS + GBLKS)              // 404

// phase D: 2047 x rows + 24 selected rows
#define NVB_D (NXUPD + ZTOPK + TOPK)       // 2071

// persistent grids: 8 blocks/CU x 256 CU, fully co-resident, grid-stride
#define GRIDA 2048
#define GRIDD 2048

__device__ __forceinline__ v4f ld4(const float* p) { return *(const v4f*)p; }
__device__ __forceinline__ v4f ld4nt(const float* p) {
  return __builtin_nontemporal_load((const v4f*)p);
}
__device__ __forceinline__ v4f v4z() { v4f v; v.x = v.y = v.z = v.w = 0.f; return v; }
__device__ __forceinline__ float dot4(v4f a, v4f b) {
  return fmaf(a.x, b.x, fmaf(a.y, b.y, fmaf(a.z, b.z, a.w * b.w)));
}
__device__ __forceinline__ v4f load_inpt(const float* x, const float* yr,
                                         const float* zv, int c) {
  int col = c * 4;   // chunk boundaries never straddle 2048 / 6144 (both %4==0)
  if (col < XS) return ld4(x + col);
  if (col < Z0) return ld4(yr + (col - XS));
  return ld4(zv + (col - Z0));
}
__device__ __forceinline__ v4f wred4(v4f a) {
  #pragma unroll
  for (int m = 32; m >= 1; m >>= 1) {
    a.x += __shfl_xor(a.x, m); a.y += __shfl_xor(a.y, m);
    a.z += __shfl_xor(a.z, m); a.w += __shfl_xor(a.w, m);
  }
  return a;
}

// ---------------- Phase A: persistent grid-stride --------------------------
// matvec + copy rows>=2047 + partial mix_x + aux. NT loads for read-once
// neurons; plain stores for big copy streams. Persistent blocks keep the
// memory pipe full across virtual-block boundaries (no per-block drain).
__global__ __launch_bounds__(256, 8) void k_pA(
    const float* __restrict__ x, const float* __restrict__ yr,
    const float* __restrict__ zv, const float* __restrict__ neurons,
    const float* __restrict__ ages, float* __restrict__ ws,
    float* __restrict__ out)
{
  const int t = threadIdx.x;
  const int lane = t & 63, wv = t >> 6;
  float* outn = out + OUT_NEUR;
  __shared__ float s_wred[4][8];
  __shared__ float s_red4[4];

  for (int vb = blockIdx.x; vb < NVB_A; vb += GRIDA) {
    if (vb < XBLKS) {
      // ---- x-part: rows rg*8..rg*8+7, columns [cs*388, +388) chunks ----
      const int rg = vb >> 2, cs = vb & 3;
      const int row0 = rg * 8;
      const int cbase = cs * CSPL;
      const int c0 = cbase + t;            // always valid (t<256<=388)
      const int c1 = cbase + 256 + t;      // valid iff t<132
      const bool has1 = (t < CSPL - 256);

      v4f i0 = load_inpt(x, yr, zv, c0);
      v4f i1 = has1 ? load_inpt(x, yr, zv, c1) : v4z();
      if (vb < 4) {  // rg==0 blocks stage inpt (each covers its column quarter)
        ((v4f*)(ws + WS_INPT))[c0] = i0;
        if (has1) ((v4f*)(ws + WS_INPT))[c1] = i1;
      }

      float dot[8];
      v4f m0 = v4z(), m1 = v4z();
      #pragma unroll
      for (int r = 0; r < 8; ++r) {
        const int row = row0 + r;
        const float* rp = neurons + (size_t)row * DD;
        float a = ages[row];
        float wr = (row < NXUPD) ? (a - 1.f) / a : 0.f;
        v4f a0 = ld4nt(rp + 4 * c0);
        v4f a1 = has1 ? ld4nt(rp + 4 * c1) : v4z();
        dot[r] = dot4(a0, i0) + dot4(a1, i1);
        m0 += wr * a0;
        m1 += wr * a1;
        if (row == 2047) {  // row 2047 is not updated — copy it to output
          *((v4f*)(outn + (size_t)2047 * DD) + c0) = a0;
          if (has1) *((v4f*)(outn + (size_t)2047 * DD) + c1) = a1;
        }
      }

      #pragma unroll
      for (int r = 0; r < 8; ++r) {
        float v = dot[r];
        #pragma unroll
        for (int m = 32; m >= 1; m >>= 1) v += __shfl_xor(v, m);
        if (lane == 0) s_wred[wv][r] = v;
      }
      __syncthreads();
      if (t < 8)
        ws[WS_RESPP + cs * 2048 + row0 + t] =
            s_wred[0][t] + s_wred[1][t] + s_wred[2][t] + s_wred[3][t];

      // partial mix_x: plain stores into dead output row rg (rows 0..255
      // are fully overwritten by phase D).
      float* pm = outn + (size_t)rg * DD;
      *(v4f*)(pm + 4 * c0) = m0;
      if (has1) *(v4f*)(pm + 4 * c1) = m1;
    } else if (vb < XBLKS + YZBLKS) {
      // ---- yz-part: one full row per virtual block, rows 2048..6207 ----
      const int row = 2048 + (vb - XBLKS);
      const float* rp = neurons + (size_t)row * DD;
      float* op = outn + (size_t)row * DD;

      v4f a[6], iv[6];
      #pragma unroll
      for (int k = 0; k < 6; ++k) a[k] = ld4nt(rp + 4 * (t + 256 * k));
      #pragma unroll
      for (int k = 0; k < 6; ++k) iv[k] = load_inpt(x, yr, zv, t + 256 * k);

      float dot = 0.f;
      #pragma unroll
      for (int k = 0; k < 6; ++k) {
        dot += dot4(a[k], iv[k]);
        *((v4f*)op + (t + 256 * k)) = a[k];
      }
      if (t < 16) {                      // epilogue chunks 1536..1551 (z region)
        const int c = 1536 + t;
        v4f ae = ld4nt(rp + 4 * c);
        v4f ie = ld4(zv + (4 * c - Z0));
        dot += dot4(ae, ie);
        *((v4f*)op + c) = ae;
      }
      #pragma unroll
      for (int m = 32; m >= 1; m >>= 1) dot += __shfl_xor(dot, m);
      if (lane == 0) s_red4[wv] = dot;
      __syncthreads();
      if (t == 0) ws[WS_RESP + row] = s_red4[0] + s_red4[1] + s_red4[2] + s_red4[3];
    } else {
      // ---- aux: ages base (+1 for x rows) and final zero-fill [XS..DD) ----
      const int e = vb - (XBLKS + YZBLKS);
      const int base = e * 1024;
      #pragma unroll
      for (int k = 0; k < 4; ++k) {
        int j = base + t + 256 * k;
        if (j < DD) {
          out[OUT_AGES + j] = ages[j] + ((j < NXUPD) ? 1.f : 0.f);
        } else {
          int f = j - DD;
          if (f < DD - XS) out[OUT_FINAL + XS + f] = 0.f;
        }
      }
    }
    __syncthreads();   // LDS reuse hazard across grid-stride iterations
  }
}

// ---------------- Phase B: 4 independent 256-thread blocks -----------------
// rb==0: y top-17; rb==1: x sum/max/denx/fin; rb==2: z top-9; rb==3: scalpad 0
__global__ __launch_bounds__(256) void k_pB(
    const float* __restrict__ ages, float* __restrict__ ws, float* __restrict__ out)
{
  const int rb = blockIdx.x;
  const int t = threadIdx.x;
  const int lane = t & 63, wv = t >> 6;
  __shared__ float smf[96];
  __shared__ int   smi[96];
  float* fin = out + OUT_FINAL;
  float* oag = out + OUT_AGES;

  if (rb == 0) {
    // ---- y top-17: 4 waves x 1024 elems, wave-local top-17 then merge ----
    float v[16]; int id[16];
    #pragma unroll
    for (int q = 0; q < 16; ++q) {
      int i = (wv << 10) + (q << 6) + lane;
      id[q] = i; v[q] = ws[WS_RESP + XS + i];
    }
    for (int j = 0; j <= TOPK; ++j) {
      float bv = v[0]; int bi = id[0];
      #pragma unroll
      for (int q = 1; q < 16; ++q)
        if (v[q] > bv || (v[q] == bv && id[q] < bi)) { bv = v[q]; bi = id[q]; }
      #pragma unroll
      for (int m = 1; m < 64; m <<= 1) {
        float ov = __shfl_xor(bv, m); int oi = __shfl_xor(bi, m);
        if (ov > bv || (ov == bv && oi < bi)) { bv = ov; bi = oi; }
      }
      if (lane == 0) { smf[wv * 17 + j] = bv; smi[wv * 17 + j] = bi; }
      #pragma unroll
      for (int q = 0; q < 16; ++q) if (id[q] == bi) v[q] = -INFINITY;
    }
    __syncthreads();
    if (wv == 0) {   // merge 68 candidates
      float mv0 = smf[lane];            int mi0 = smi[lane];
      float mv1 = (lane < 4) ? smf[64 + lane] : -INFINITY;
      int   mi1 = (lane < 4) ? smi[64 + lane] : 0x7fffffff;
      for (int j = 0; j <= TOPK; ++j) {
        float bv = mv0; int bi = mi0;
        if (mv1 > bv || (mv1 == bv && mi1 < bi)) { bv = mv1; bi = mi1; }
        #pragma unroll
        for (int m = 1; m < 64; m <<= 1) {
          float ov = __shfl_xor(bv, m); int oi = __shfl_xor(bi, m);
          if (ov > bv || (ov == bv && oi < bi)) { bv = ov; bi = oi; }
        }
        if (lane == 0) { smf[68 + j] = bv; smi[68 + j] = bi; }
        if (mi0 == bi) mv0 = -INFINITY;
        if (mi1 == bi) mv1 = -INFINITY;
      }
    }
    __syncthreads();
    if (t == 0) {
      float ylast = smf[68 + TOPK];
      float ty = 0.f;
      for (int q = 0; q < TOPK; ++q) if (smf[68 + q] == ylast) ty = 1.f;
      smf[85] = ty;
    }
    __syncthreads();
    if (t < TOPK) {
      float ylast = smf[68 + TOPK];
      float yden = smf[68] - ylast + EPS_TIE * smf[85] * RNDC;
      int row = XS + smi[68 + t];
      fin[row] = (smf[68 + t] - ylast) / yden;
      float a = ages[row];
      ((int*)(ws + WS_SELROW))[ZTOPK + t] = row;
      ws[WS_SELC + ZTOPK + t] = smf[68 + t] / a;
      ws[WS_SELW + ZTOPK + t] = (a - 1.f) / a;
      oag[row] = a + 1.f;
    }
  } else if (rb == 1) {
    // ---- x: sum 4 partials, max & nz -> denx; write xsum and fin[x] ----
    float s[8]; float lm = -INFINITY; int nz = 0;
    #pragma unroll
    for (int k = 0; k < 8; ++k) {
      int i = t + 256 * k;
      float v = ws[WS_RESPP + i] + ws[WS_RESPP + 2048 + i] +
                ws[WS_RESPP + 4096 + i] + ws[WS_RESPP + 6144 + i];
      s[k] = v;
      ws[WS_RESP + i] = v;
      lm = fmaxf(lm, v); nz |= (v != 0.f);
    }
    #pragma unroll
    for (int m = 1; m < 64; m <<= 1) { lm = fmaxf(lm, __shfl_xor(lm, m)); nz |= __shfl_xor(nz, m); }
    if (lane == 0) { smf[wv] = lm; smi[wv] = nz; }
    __syncthreads();
    if (t == 0) {
      float m2 = fmaxf(fmaxf(smf[0], smf[1]), fmaxf(smf[2], smf[3]));
      int n2 = smi[0] | smi[1] | smi[2] | smi[3];
      float dx = m2 + EPS_TIE * (n2 ? 0.f : 1.f) * RNDC;
      smf[4] = dx; ws[WS_SCAL + 7] = dx;
    }
    __syncthreads();
    float dx = smf[4];
    #pragma unroll
    for (int k = 0; k < 8; ++k) fin[t + 256 * k] = s[k] / dx;
  } else if (rb == 2) {
    // ---- z top-9 (wave 0) + scatters + z_response ----
    if (wv == 0) {
      float v = ws[WS_RESP + Z0 + lane];
      for (int j = 0; j <= ZTOPK; ++j) {
        float bv = v; int bi = lane;
        #pragma unroll
        for (int m = 1; m < 64; m <<= 1) {
          float ov = __shfl_xor(bv, m); int oi = __shfl_xor(bi, m);
          if (ov > bv || (ov == bv && oi < bi)) { bv = ov; bi = oi; }
        }
        if (lane == 0) { smf[j] = bv; smi[j] = bi; }
        if (lane == bi) v = -INFINITY;
      }
    }
    __syncthreads();
    float zlast = smf[ZTOPK], zden = smf[0] - zlast;
    if (t < ZTOPK) {
      int row = Z0 + smi[t];
      fin[row] = (smf[t] - zlast) / zden;
      float a = ages[row];
      ((int*)(ws + WS_SELROW))[t] = row;
      ws[WS_SELC + t] = smf[t] / a;
      ws[WS_SELW + t] = (a - 1.f) / a;
      oag[row] = a + 1.f;
    }
    if (t >= 128 && t < 192) {
      int i = t - 128;
      float v = 0.f;
      for (int k = 0; k < ZTOPK; ++k) if (smi[k] == i) v = (smf[k] - zlast) / zden;
      out[i] = v;
    }
  } else {
    // ---- zero the 448-slot scalar pad for phase C atomics ----
    ws[WS_SCALPAD + t] = 0.f;
    if (t < 192) ws[WS_SCALPAD + 256 + t] = 0.f;
  }
}

// ---------------- Phase C: mix_x reduce + z/y gather + scalars -------------
__global__ __launch_bounds__(256, 4) void k_pC(
    const float* __restrict__ neurons, const float* __restrict__ outn,
    float* __restrict__ ws)
{
  const int vb = blockIdx.x;
  const int t = threadIdx.x;
  const int lane = t & 63, wv = t >> 6;
  __shared__ float smf[96];

  if (vb < RBLKS) {
    // mix_x tree-reduce: sum 256 partial rows (outn rows 0..255) for 4 chunks
    const int cb = 4 * vb;
    const float* pr = outn + (size_t)t * DD + 4 * cb;
    v4f a0 = ld4(pr), a1 = ld4(pr + 4), a2 = ld4(pr + 8), a3 = ld4(pr + 12);
    a0 = wred4(a0); a1 = wred4(a1); a2 = wred4(a2); a3 = wred4(a3);
    v4f* sred = (v4f*)smf;       // 16 v4f = 64 floats
    float* sp = smf + 64;        // 12 floats
    if (lane == 0) {
      sred[wv * 4 + 0] = a0; sred[wv * 4 + 1] = a1;
      sred[wv * 4 + 2] = a2; sred[wv * 4 + 3] = a3;
    }
    __syncthreads();
    if (t < 4) {
      v4f s = sred[t] + sred[4 + t] + sred[8 + t] + sred[12 + t];
      *(v4f*)(ws + WS_MIXX + 4 * (cb + t)) = s;
      v4f ip = ld4(ws + WS_INPT + 4 * (cb + t));
      sp[t * 3 + 0] = dot4(ip, ip);
      sp[t * 3 + 1] = dot4(s, s);
      sp[t * 3 + 2] = dot4(s, ip);
    }
    __syncthreads();
    if (t == 0) {
      const int slot = vb & 63;
      #pragma unroll
      for (int k = 0; k < 3; ++k) {
        float p = sp[k] + sp[3 + k] + sp[6 + k] + sp[9 + k];
        atomicAdd(ws + WS_SCALPAD + k * 64 + slot, p);
      }
    }
  } else {
    // gather mix_z (8 sel rows) and mix_y (16 sel rows) for 97 chunks
    const int g = vb - RBLKS;            // 0..15
    const int c = 97 * g + t;            // valid iff t<97
    const int* selr = (const int*)(ws + WS_SELROW);
    float p0 = 0.f, p1 = 0.f, p2 = 0.f, p3 = 0.f;
    if (t < 97) {
      v4f mz = v4z(), my = v4z();
      #pragma unroll
      for (int k = 0; k < ZTOPK; ++k) {
        const int row = selr[k];
        const float w = ws[WS_SELW + k];
        mz += w * ld4(neurons + (size_t)row * DD + 4 * c);
      }
      #pragma unroll
      for (int k = ZTOPK; k < ZTOPK + TOPK; ++k) {
        const int row = selr[k];
        const float w = ws[WS_SELW + k];
        my += w * ld4(neurons + (size_t)row * DD + 4 * c);
      }
      *(v4f*)(ws + WS_MIXZ + 4 * c) = mz;
      *(v4f*)(ws + WS_MIXY + 4 * c) = my;
      v4f ip = ld4(ws + WS_INPT + 4 * c);
      p0 = dot4(mz, mz); p1 = dot4(mz, ip);
      p2 = dot4(my, my); p3 = dot4(my, ip);
    }
    #pragma unroll
    for (int m = 1; m < 64; m <<= 1) {
      p0 += __shfl_xor(p0, m); p1 += __shfl_xor(p1, m);
      p2 += __shfl_xor(p2, m); p3 += __shfl_xor(p3, m);
    }
    float* gr = smf;             // 16 floats
    if (lane == 0) {
      gr[wv * 4 + 0] = p0; gr[wv * 4 + 1] = p1;
      gr[wv * 4 + 2] = p2; gr[wv * 4 + 3] = p3;
    }
    __syncthreads();
    if (t == 0) {
      const int slot = vb & 63;
      #pragma unroll
      for (int k = 0; k < 4; ++k) {
        float p = gr[k] + gr[4 + k] + gr[8 + k] + gr[12 + k];
        atomicAdd(ws + WS_SCALPAD + (3 + k) * 64 + slot, p);
      }
    }
  }
}

// ---------------- Phase D: persistent grid-stride row writer ---------------
__global__ __launch_bounds__(256, 8) void k_pD(
    const float* __restrict__ ages, const float* __restrict__ ws,
    float* __restrict__ outn)
{
  const int t = threadIdx.x;

  // reduce the scalar pad (7 scalars x 64 slots) in wave 0, once per block
  __shared__ float s_scal[7];
  if (t < 64) {
    #pragma unroll
    for (int k = 0; k < 7; ++k) {
      float v = ws[WS_SCALPAD + k * 64 + t];
      #pragma unroll
      for (int m = 1; m < 64; m <<= 1) v += __shfl_xor(v, m);
      if (t == 0) s_scal[k] = v;
    }
  }
  __syncthreads();
  const float sii = s_scal[0];

  for (int vb = blockIdx.x; vb < NVB_D; vb += GRIDD) {
    int row; float c, smm, smi_; const float* mix;
    if (vb < NXUPD) {
      row = vb;
      float a = ages[row];
      c = (ws[WS_RESP + row] / ws[WS_SCAL + 7]) / a;   // xvals[row] / age
      mix = ws + WS_MIXX; smm = s_scal[1]; smi_ = s_scal[2];
    } else {
      int k = vb - NXUPD;
      row = ((const int*)(ws + WS_SELROW))[k];
      c = ws[WS_SELC + k];
      if (k < ZTOPK) { mix = ws + WS_MIXZ; smm = s_scal[3]; smi_ = s_scal[4]; }
      else           { mix = ws + WS_MIXY; smm = s_scal[5]; smi_ = s_scal[6]; }
    }
    // ||mix + c*inpt||^2 = smm + 2c*smi + c^2*sii
    const float inv = 1.f / (sqrtf(fmaf(c, fmaf(c, sii, 2.f * smi_), smm)) + 1e-12f);
    const float* inpt = ws + WS_INPT;
    float* dst = outn + (size_t)row * DD;
    #pragma unroll
    for (int k = 0; k < 6; ++k) {
      const int i = t + 256 * k;
      v4f m4 = ((const v4f*)(mix))[i];
      v4f i4 = ((const v4f*)(inpt))[i];
      v4f o = (m4 + c * i4) * inv;
      *((v4f*)dst + i) = o;
    }
    if (t < 16) {
      const int i = 1536 + t;
      v4f m4 = ((const v4f*)(mix))[i];
      v4f i4 = ((const v4f*)(inpt))[i];
      v4f o = (m4 + c * i4) * inv;
      *((v4f*)dst + i) = o;
    }
  }
}

// ---------------- launcher -------------------------------------------------
extern "C" void kernel_launch(void* const* d_in, const int* in_sizes, int n_in,
                              void* d_out, int out_size, void* d_ws, size_t ws_size,
                              hipStream_t stream)
{
  (void)in_sizes; (void)n_in; (void)out_size; (void)ws_size;
  const float* x    = (const float*)d_in[0];
  const float* zin  = (const float*)d_in[1];   // setup order: x, z, y_response, neurons, ages
  const float* yr   = (const float*)d_in[2];
  const float* neur = (const float*)d_in[3];
  const float* ages = (const float*)d_in[4];
  float* out = (float*)d_out;
  float* ws  = (float*)d_ws;

  k_pA<<<GRIDA, 256, 0, stream>>>(x, yr, zin, neur, ages, ws, out);
  k_pB<<<4, 256, 0, stream>>>(ages, ws, out);
  k_pC<<<NVB_C, 256, 0, stream>>>(neur, out + OUT_NEUR, ws);
  k_pD<<<GRIDD, 256, 0, stream>>>(ages, ws, out + OUT_NEUR);
}

// Round 6
// 306.056 us; speedup vs baseline: 1.1784x; 1.1784x over previous
//
#include <hip/hip_runtime.h>
#include <math.h>

typedef float v4f __attribute__((ext_vector_type(4)));

#define XS 2048
#define NN 4096
#define ZS 64
#define DD 6208
#define D4 1552              // DD/4 chunks per row
#define Z0 (XS + NN)         // 6144
#define TOPK 16
#define ZTOPK 8
#define EPS_TIE 1e-9f
#define RNDC 0.5f
#define NXUPD 2047           // x rows updated: 0..2046

// d_out offsets (floats): [z_response(64) | final(6208) | neurons(DD*DD) | ages(6208)]
#define OUT_FINAL 64
#define OUT_NEUR  (64 + DD)
#define OUT_AGES  (OUT_NEUR + (size_t)DD * DD)

// ws offsets (floats) — no region requires pre-zeroing by the host
#define WS_RESP    0                         // [0,2048): xsum (phase B); [2048,6208): yz dots (phase A)
#define WS_RESPP   DD                        // 4 x 2048 x-row dot partials
#define WS_INPT    (DD + 8192)
#define WS_MIXX    (WS_INPT + DD)
#define WS_MIXZ    (WS_MIXX + DD)
#define WS_MIXY    (WS_MIXZ + DD)
#define WS_SCAL    (WS_MIXY + DD)            // [7] = denomX (written by phase B)
#define WS_SCALPAD (WS_SCAL + 32)            // 7 scalars x 64 slots (zeroed by phase B blk3)
#define WS_SELROW  (WS_SCALPAD + 448)        // 24 ints
#define WS_SELC    (WS_SELROW + 24)          // 24 floats: v/a
#define WS_SELW    (WS_SELC + 24)            // 24 floats: (a-1)/a
#define WS_TOTAL   (WS_SELW + 32)

// scalpad scalar ids: 0 Sii, 1 SmmX, 2 SmiX, 3 SmmZ, 4 SmiZ, 5 SmmY, 6 SmiY

// phase A: 256 row-groups (8 rows) x 4 col splits + 4160 yz rows + 11 aux
#define XBLKS 1024
#define CSPL  388
#define YZBLKS (DD - XS)             // 4160
#define AUXBLKS 11
#define NVB_A (XBLKS + YZBLKS + AUXBLKS)   // 5195

// phase C: 388 mix_x reduce + 16 gather
#define RBLKS 388
#define GBLKS 16
#define NVB_C (RBLKS + GBLKS)              // 404

// phase D: 2047 x rows + 24 selected rows
#define NVB_D (NXUPD + ZTOPK + TOPK)       // 2071

__device__ __forceinline__ v4f ld4(const float* p) { return *(const v4f*)p; }
__device__ __forceinline__ v4f ld4nt(const float* p) {
  return __builtin_nontemporal_load((const v4f*)p);
}
__device__ __forceinline__ void st4nt(float* p, v4f v) {
  __builtin_nontemporal_store(v, (v4f*)p);
}
__device__ __forceinline__ v4f v4z() { v4f v; v.x = v.y = v.z = v.w = 0.f; return v; }
__device__ __forceinline__ float dot4(v4f a, v4f b) {
  return fmaf(a.x, b.x, fmaf(a.y, b.y, fmaf(a.z, b.z, a.w * b.w)));
}
__device__ __forceinline__ v4f load_inpt(const float* x, const float* yr,
                                         const float* zv, int c) {
  int col = c * 4;   // chunk boundaries never straddle 2048 / 6144 (both %4==0)
  if (col < XS) return ld4(x + col);
  if (col < Z0) return ld4(yr + (col - XS));
  return ld4(zv + (col - Z0));
}
__device__ __forceinline__ v4f wred4(v4f a) {
  #pragma unroll
  for (int m = 32; m >= 1; m >>= 1) {
    a.x += __shfl_xor(a.x, m); a.y += __shfl_xor(a.y, m);
    a.z += __shfl_xor(a.z, m); a.w += __shfl_xor(a.w, m);
  }
  return a;
}

// ---------------- Phase A: matvec + copy rows>=2047 + partial mix_x + aux --
// NT loads for read-once neurons; NT stores for never-re-read streams
// (yz copy, row-2047 copy, ages/final aux) to avoid L2 write-amplification
// (round-5 PMC: plain-store copy doubled WRITE_SIZE, 238 MB vs ~110 MB real).
// Plain stores only for data re-read by later phases (mix partials, ws).
__global__ __launch_bounds__(256, 4) void k_pA(
    const float* __restrict__ x, const float* __restrict__ yr,
    const float* __restrict__ zv, const float* __restrict__ neurons,
    const float* __restrict__ ages, float* __restrict__ ws,
    float* __restrict__ out)
{
  const int t = threadIdx.x;
  const int vb = blockIdx.x;
  float* outn = out + OUT_NEUR;

  if (vb < XBLKS) {
    // ---- x-part: rows rg*8..rg*8+7, columns [cs*388, cs*388+388) chunks ----
    const int rg = vb >> 2, cs = vb & 3;
    const int row0 = rg * 8;
    const int cbase = cs * CSPL;
    const int c0 = cbase + t;            // always valid (t<256<=388)
    const int c1 = cbase + 256 + t;      // valid iff t<132
    const bool has1 = (t < CSPL - 256);

    v4f i0 = load_inpt(x, yr, zv, c0);
    v4f i1 = has1 ? load_inpt(x, yr, zv, c1) : v4z();
    if (vb < 4) {  // rg==0 blocks stage inpt (each covers its column quarter)
      ((v4f*)(ws + WS_INPT))[c0] = i0;
      if (has1) ((v4f*)(ws + WS_INPT))[c1] = i1;
    }

    float dot[8];
    v4f m0 = v4z(), m1 = v4z();
    #pragma unroll
    for (int r = 0; r < 8; ++r) {
      const int row = row0 + r;
      const float* rp = neurons + (size_t)row * DD;
      float a = ages[row];
      float wr = (row < NXUPD) ? (a - 1.f) / a : 0.f;
      v4f a0 = ld4nt(rp + 4 * c0);
      v4f a1 = has1 ? ld4nt(rp + 4 * c1) : v4z();
      dot[r] = dot4(a0, i0) + dot4(a1, i1);
      m0 += wr * a0;
      m1 += wr * a1;
      if (row == 2047) {  // row 2047 is not updated — copy it to output
        st4nt(outn + (size_t)2047 * DD + 4 * c0, a0);
        if (has1) st4nt(outn + (size_t)2047 * DD + 4 * c1, a1);
      }
    }

    const int lane = t & 63, wv = t >> 6;
    __shared__ float s_wred[4][8];
    #pragma unroll
    for (int r = 0; r < 8; ++r) {
      float v = dot[r];
      #pragma unroll
      for (int m = 32; m >= 1; m >>= 1) v += __shfl_xor(v, m);
      if (lane == 0) s_wred[wv][r] = v;
    }
    __syncthreads();
    if (t < 8)
      ws[WS_RESPP + cs * 2048 + row0 + t] =
          s_wred[0][t] + s_wred[1][t] + s_wred[2][t] + s_wred[3][t];

    // partial mix_x: plain stores into dead output row rg (rows 0..255 are
    // fully overwritten by phase D; re-read by phase C soon → keep in L2).
    float* pm = outn + (size_t)rg * DD;
    *(v4f*)(pm + 4 * c0) = m0;
    if (has1) *(v4f*)(pm + 4 * c1) = m1;
  } else if (vb < XBLKS + YZBLKS) {
    // ---- yz-part: one full row per block, rows 2048..6207 ----
    const int row = 2048 + (vb - XBLKS);
    const float* rp = neurons + (size_t)row * DD;
    float* op = outn + (size_t)row * DD;

    v4f a[6], iv[6];
    #pragma unroll
    for (int k = 0; k < 6; ++k) a[k] = ld4nt(rp + 4 * (t + 256 * k));
    #pragma unroll
    for (int k = 0; k < 6; ++k) iv[k] = load_inpt(x, yr, zv, t + 256 * k);

    float dot = 0.f;
    #pragma unroll
    for (int k = 0; k < 6; ++k) {
      dot += dot4(a[k], iv[k]);
      st4nt(op + 4 * (t + 256 * k), a[k]);
    }
    if (t < 16) {                        // epilogue chunks 1536..1551 (z region)
      const int c = 1536 + t;
      v4f ae = ld4nt(rp + 4 * c);
      v4f ie = ld4(zv + (4 * c - Z0));
      dot += dot4(ae, ie);
      st4nt(op + 4 * c, ae);
    }
    const int lane = t & 63, wv = t >> 6;
    __shared__ float s_red4[4];
    #pragma unroll
    for (int m = 32; m >= 1; m >>= 1) dot += __shfl_xor(dot, m);
    if (lane == 0) s_red4[wv] = dot;
    __syncthreads();
    if (t == 0) ws[WS_RESP + row] = s_red4[0] + s_red4[1] + s_red4[2] + s_red4[3];
  } else {
    // ---- aux: ages base (+1 for x rows) and final zero-fill [XS..DD) ----
    const int e = vb - (XBLKS + YZBLKS);
    const int base = e * 1024;
    #pragma unroll
    for (int k = 0; k < 4; ++k) {
      int j = base + t + 256 * k;
      if (j < DD) {
        float v = ages[j] + ((j < NXUPD) ? 1.f : 0.f);
        __builtin_nontemporal_store(v, out + OUT_AGES + j);
      } else {
        int f = j - DD;
        if (f < DD - XS) __builtin_nontemporal_store(0.f, out + OUT_FINAL + XS + f);
      }
    }
  }
}

// ---------------- Phase B: 4 independent 256-thread blocks -----------------
// rb==0: y top-17; rb==1: x sum/max/denx/fin; rb==2: z top-9; rb==3: scalpad 0
__global__ __launch_bounds__(256) void k_pB(
    const float* __restrict__ ages, float* __restrict__ ws, float* __restrict__ out)
{
  const int rb = blockIdx.x;
  const int t = threadIdx.x;
  const int lane = t & 63, wv = t >> 6;
  __shared__ float smf[96];
  __shared__ int   smi[96];
  float* fin = out + OUT_FINAL;
  float* oag = out + OUT_AGES;

  if (rb == 0) {
    // ---- y top-17: 4 waves x 1024 elems, wave-local top-17 then merge ----
    float v[16]; int id[16];
    #pragma unroll
    for (int q = 0; q < 16; ++q) {
      int i = (wv << 10) + (q << 6) + lane;
      id[q] = i; v[q] = ws[WS_RESP + XS + i];
    }
    for (int j = 0; j <= TOPK; ++j) {
      float bv = v[0]; int bi = id[0];
      #pragma unroll
      for (int q = 1; q < 16; ++q)
        if (v[q] > bv || (v[q] == bv && id[q] < bi)) { bv = v[q]; bi = id[q]; }
      #pragma unroll
      for (int m = 1; m < 64; m <<= 1) {
        float ov = __shfl_xor(bv, m); int oi = __shfl_xor(bi, m);
        if (ov > bv || (ov == bv && oi < bi)) { bv = ov; bi = oi; }
      }
      if (lane == 0) { smf[wv * 17 + j] = bv; smi[wv * 17 + j] = bi; }
      #pragma unroll
      for (int q = 0; q < 16; ++q) if (id[q] == bi) v[q] = -INFINITY;
    }
    __syncthreads();
    if (wv == 0) {   // merge 68 candidates
      float mv0 = smf[lane];            int mi0 = smi[lane];
      float mv1 = (lane < 4) ? smf[64 + lane] : -INFINITY;
      int   mi1 = (lane < 4) ? smi[64 + lane] : 0x7fffffff;
      for (int j = 0; j <= TOPK; ++j) {
        float bv = mv0; int bi = mi0;
        if (mv1 > bv || (mv1 == bv && mi1 < bi)) { bv = mv1; bi = mi1; }
        #pragma unroll
        for (int m = 1; m < 64; m <<= 1) {
          float ov = __shfl_xor(bv, m); int oi = __shfl_xor(bi, m);
          if (ov > bv || (ov == bv && oi < bi)) { bv = ov; bi = oi; }
        }
        if (lane == 0) { smf[68 + j] = bv; smi[68 + j] = bi; }
        if (mi0 == bi) mv0 = -INFINITY;
        if (mi1 == bi) mv1 = -INFINITY;
      }
    }
    __syncthreads();
    if (t == 0) {
      float ylast = smf[68 + TOPK];
      float ty = 0.f;
      for (int q = 0; q < TOPK; ++q) if (smf[68 + q] == ylast) ty = 1.f;
      smf[85] = ty;
    }
    __syncthreads();
    if (t < TOPK) {
      float ylast = smf[68 + TOPK];
      float yden = smf[68] - ylast + EPS_TIE * smf[85] * RNDC;
      int row = XS + smi[68 + t];
      fin[row] = (smf[68 + t] - ylast) / yden;
      float a = ages[row];
      ((int*)(ws + WS_SELROW))[ZTOPK + t] = row;
      ws[WS_SELC + ZTOPK + t] = smf[68 + t] / a;
      ws[WS_SELW + ZTOPK + t] = (a - 1.f) / a;
      oag[row] = a + 1.f;
    }
  } else if (rb == 1) {
    // ---- x: sum 4 partials, max & nz -> denx; write xsum and fin[x] ----
    float s[8]; float lm = -INFINITY; int nz = 0;
    #pragma unroll
    for (int k = 0; k < 8; ++k) {
      int i = t + 256 * k;
      float v = ws[WS_RESPP + i] + ws[WS_RESPP + 2048 + i] +
                ws[WS_RESPP + 4096 + i] + ws[WS_RESPP + 6144 + i];
      s[k] = v;
      ws[WS_RESP + i] = v;
      lm = fmaxf(lm, v); nz |= (v != 0.f);
    }
    #pragma unroll
    for (int m = 1; m < 64; m <<= 1) { lm = fmaxf(lm, __shfl_xor(lm, m)); nz |= __shfl_xor(nz, m); }
    if (lane == 0) { smf[wv] = lm; smi[wv] = nz; }
    __syncthreads();
    if (t == 0) {
      float m2 = fmaxf(fmaxf(smf[0], smf[1]), fmaxf(smf[2], smf[3]));
      int n2 = smi[0] | smi[1] | smi[2] | smi[3];
      float dx = m2 + EPS_TIE * (n2 ? 0.f : 1.f) * RNDC;
      smf[4] = dx; ws[WS_SCAL + 7] = dx;
    }
    __syncthreads();
    float dx = smf[4];
    #pragma unroll
    for (int k = 0; k < 8; ++k) fin[t + 256 * k] = s[k] / dx;
  } else if (rb == 2) {
    // ---- z top-9 (wave 0) + scatters + z_response ----
    if (wv == 0) {
      float v = ws[WS_RESP + Z0 + lane];
      for (int j = 0; j <= ZTOPK; ++j) {
        float bv = v; int bi = lane;
        #pragma unroll
        for (int m = 1; m < 64; m <<= 1) {
          float ov = __shfl_xor(bv, m); int oi = __shfl_xor(bi, m);
          if (ov > bv || (ov == bv && oi < bi)) { bv = ov; bi = oi; }
        }
        if (lane == 0) { smf[j] = bv; smi[j] = bi; }
        if (lane == bi) v = -INFINITY;
      }
    }
    __syncthreads();
    float zlast = smf[ZTOPK], zden = smf[0] - zlast;
    if (t < ZTOPK) {
      int row = Z0 + smi[t];
      fin[row] = (smf[t] - zlast) / zden;
      float a = ages[row];
      ((int*)(ws + WS_SELROW))[t] = row;
      ws[WS_SELC + t] = smf[t] / a;
      ws[WS_SELW + t] = (a - 1.f) / a;
      oag[row] = a + 1.f;
    }
    if (t >= 128 && t < 192) {
      int i = t - 128;
      float v = 0.f;
      for (int k = 0; k < ZTOPK; ++k) if (smi[k] == i) v = (smf[k] - zlast) / zden;
      out[i] = v;
    }
  } else {
    // ---- zero the 448-slot scalar pad for phase C atomics ----
    ws[WS_SCALPAD + t] = 0.f;
    if (t < 192) ws[WS_SCALPAD + 256 + t] = 0.f;
  }
}

// ---------------- Phase C: mix_x reduce + z/y gather + scalars -------------
__global__ __launch_bounds__(256, 4) void k_pC(
    const float* __restrict__ neurons, const float* __restrict__ outn,
    float* __restrict__ ws)
{
  const int vb = blockIdx.x;
  const int t = threadIdx.x;
  const int lane = t & 63, wv = t >> 6;
  __shared__ float smf[96];

  if (vb < RBLKS) {
    // mix_x tree-reduce: sum 256 partial rows (outn rows 0..255) for 4 chunks
    const int cb = 4 * vb;
    const float* pr = outn + (size_t)t * DD + 4 * cb;
    v4f a0 = ld4(pr), a1 = ld4(pr + 4), a2 = ld4(pr + 8), a3 = ld4(pr + 12);
    a0 = wred4(a0); a1 = wred4(a1); a2 = wred4(a2); a3 = wred4(a3);
    v4f* sred = (v4f*)smf;       // 16 v4f = 64 floats
    float* sp = smf + 64;        // 12 floats
    if (lane == 0) {
      sred[wv * 4 + 0] = a0; sred[wv * 4 + 1] = a1;
      sred[wv * 4 + 2] = a2; sred[wv * 4 + 3] = a3;
    }
    __syncthreads();
    if (t < 4) {
      v4f s = sred[t] + sred[4 + t] + sred[8 + t] + sred[12 + t];
      *(v4f*)(ws + WS_MIXX + 4 * (cb + t)) = s;
      v4f ip = ld4(ws + WS_INPT + 4 * (cb + t));
      sp[t * 3 + 0] = dot4(ip, ip);
      sp[t * 3 + 1] = dot4(s, s);
      sp[t * 3 + 2] = dot4(s, ip);
    }
    __syncthreads();
    if (t == 0) {
      const int slot = vb & 63;
      #pragma unroll
      for (int k = 0; k < 3; ++k) {
        float p = sp[k] + sp[3 + k] + sp[6 + k] + sp[9 + k];
        atomicAdd(ws + WS_SCALPAD + k * 64 + slot, p);
      }
    }
  } else {
    // gather mix_z (8 sel rows) and mix_y (16 sel rows) for 97 chunks
    const int g = vb - RBLKS;            // 0..15
    const int c = 97 * g + t;            // valid iff t<97
    const int* selr = (const int*)(ws + WS_SELROW);
    float p0 = 0.f, p1 = 0.f, p2 = 0.f, p3 = 0.f;
    if (t < 97) {
      v4f mz = v4z(), my = v4z();
      #pragma unroll
      for (int k = 0; k < ZTOPK; ++k) {
        const int row = selr[k];
        const float w = ws[WS_SELW + k];
        mz += w * ld4(neurons + (size_t)row * DD + 4 * c);
      }
      #pragma unroll
      for (int k = ZTOPK; k < ZTOPK + TOPK; ++k) {
        const int row = selr[k];
        const float w = ws[WS_SELW + k];
        my += w * ld4(neurons + (size_t)row * DD + 4 * c);
      }
      *(v4f*)(ws + WS_MIXZ + 4 * c) = mz;
      *(v4f*)(ws + WS_MIXY + 4 * c) = my;
      v4f ip = ld4(ws + WS_INPT + 4 * c);
      p0 = dot4(mz, mz); p1 = dot4(mz, ip);
      p2 = dot4(my, my); p3 = dot4(my, ip);
    }
    #pragma unroll
    for (int m = 1; m < 64; m <<= 1) {
      p0 += __shfl_xor(p0, m); p1 += __shfl_xor(p1, m);
      p2 += __shfl_xor(p2, m); p3 += __shfl_xor(p3, m);
    }
    float* gr = smf;             // 16 floats
    if (lane == 0) {
      gr[wv * 4 + 0] = p0; gr[wv * 4 + 1] = p1;
      gr[wv * 4 + 2] = p2; gr[wv * 4 + 3] = p3;
    }
    __syncthreads();
    if (t == 0) {
      const int slot = vb & 63;
      #pragma unroll
      for (int k = 0; k < 4; ++k) {
        float p = gr[k] + gr[4 + k] + gr[8 + k] + gr[12 + k];
        atomicAdd(ws + WS_SCALPAD + (3 + k) * 64 + slot, p);
      }
    }
  }
}

// ---------------- Phase D: write the 2071 updated rows ---------------------
__global__ __launch_bounds__(256, 4) void k_pD(
    const float* __restrict__ ages, const float* __restrict__ ws,
    float* __restrict__ outn)
{
  const int vb = blockIdx.x;
  const int t = threadIdx.x;

  // reduce the scalar pad (7 scalars x 64 slots) in wave 0
  __shared__ float s_scal[7];
  if (t < 64) {
    #pragma unroll
    for (int k = 0; k < 7; ++k) {
      float v = ws[WS_SCALPAD + k * 64 + t];
      #pragma unroll
      for (int m = 1; m < 64; m <<= 1) v += __shfl_xor(v, m);
      if (t == 0) s_scal[k] = v;
    }
  }
  __syncthreads();

  const float sii = s_scal[0];
  int row; float c, smm, smi_; const float* mix;
  if (vb < NXUPD) {
    row = vb;
    float a = ages[row];
    c = (ws[WS_RESP + row] / ws[WS_SCAL + 7]) / a;   // xvals[row] / age
    mix = ws + WS_MIXX; smm = s_scal[1]; smi_ = s_scal[2];
  } else {
    int k = vb - NXUPD;
    row = ((const int*)(ws + WS_SELROW))[k];
    c = ws[WS_SELC + k];
    if (k < ZTOPK) { mix = ws + WS_MIXZ; smm = s_scal[3]; smi_ = s_scal[4]; }
    else           { mix = ws + WS_MIXY; smm = s_scal[5]; smi_ = s_scal[6]; }
  }
  // ||mix + c*inpt||^2 = smm + 2c*smi + c^2*sii
  const float inv = 1.f / (sqrtf(fmaf(c, fmaf(c, sii, 2.f * smi_), smm)) + 1e-12f);
  const float* inpt = ws + WS_INPT;
  float* dst = outn + (size_t)row * DD;
  #pragma unroll
  for (int k = 0; k < 6; ++k) {
    const int i = t + 256 * k;
    v4f m4 = ((const v4f*)(mix))[i];
    v4f i4 = ((const v4f*)(inpt))[i];
    v4f o = (m4 + c * i4) * inv;
    st4nt(dst + 4 * i, o);
  }
  if (t < 16) {
    const int i = 1536 + t;
    v4f m4 = ((const v4f*)(mix))[i];
    v4f i4 = ((const v4f*)(inpt))[i];
    v4f o = (m4 + c * i4) * inv;
    st4nt(dst + 4 * i, o);
  }
}

// ---------------- launcher -------------------------------------------------
extern "C" void kernel_launch(void* const* d_in, const int* in_sizes, int n_in,
                              void* d_out, int out_size, void* d_ws, size_t ws_size,
                              hipStream_t stream)
{
  (void)in_sizes; (void)n_in; (void)out_size; (void)ws_size;
  const float* x    = (const float*)d_in[0];
  const float* zin  = (const float*)d_in[1];   // setup order: x, z, y_response, neurons, ages
  const float* yr   = (const float*)d_in[2];
  const float* neur = (const float*)d_in[3];
  const float* ages = (const float*)d_in[4];
  float* out = (float*)d_out;
  float* ws  = (float*)d_ws;

  k_pA<<<NVB_A, 256, 0, stream>>>(x, yr, zin, neur, ages, ws, out);
  k_pB<<<4, 256, 0, stream>>>(ages, ws, out);
  k_pC<<<NVB_C, 256, 0, stream>>>(neur, out + OUT_NEUR, ws);
  k_pD<<<NVB_D, 256, 0, stream>>>(ages, ws, out + OUT_NEUR);
}